// Round 8
// baseline (195.768 us; speedup 1.0000x reference)
//
#include <hip/hip_runtime.h>

#define BB 32768
#define BS (BB*16)   // 524288

typedef float v2f __attribute__((ext_vector_type(2)));
__device__ __forceinline__ v2f spl(float s){ return (v2f){s, s}; }

// ---- ws float offsets ----
#define H0   0               // h0f[16] c0f[16] h0b[16] c0b[16]
#define RECO 64              // rec[16]
#define TAB  128             // disc F table, 2049 floats over [-8,8], step 1/128
#define NTAB 2049
#define HFO  8448            // final h fwd, B*16 floats
#define HBO  (HFO+BS)        // final h bwd

// ---- k_init LDS layout: gate-major (i,g,o; f dropped), padded row strides ----
#define PW0 0
#define PB0 96
#define PW1 192    // 48 rows x 36
#define PB1 1920
#define PW2 1968   // 24 rows x 20
#define PB2 2448
#define PW3 2472   // 48 rows x 12
#define PB3 3048
#define PW4 3096   // 96 rows x 20
#define PB4 5016
#define POW 5112
#define POB 5144
#define PN  5148

__device__ __forceinline__ float sigm(float x){
    return __builtin_amdgcn_rcpf(1.f + __expf(-x));
}
__device__ __forceinline__ float tanh_f(float x){
    return 1.f - 2.f * __builtin_amdgcn_rcpf(1.f + __expf(2.f * x));
}
__device__ __forceinline__ float dunit(float gi, float gg, float go){
    return sigm(go) * tanh_f(sigm(gi) * tanh_f(gg));
}

struct P29 { const float* p[29]; };
// 0 values 1 masks 2-4 g_fwd(Wih,Whh,b) 5-7 g_bwd 8 impW 9 impb
// 10 fcW 11 fcb 12-14 dec(Wih,Whh,b) 15 dec_out_W 16 dec_out_b 17 disc_out_W
// 18 disc_out_b 19/20 d_W_0/d_b_0 ... 27/28 d_W_4/d_b_4

// ---- k_init: 16 lanes per table entry; block 128 = init states + decoder.
//      waves_per_eu(1,1): only 129 blocks -> occupancy irrelevant; give the
//      allocator the whole VGPR file so A0..A3 never spill to scratch. ----
__global__ __launch_bounds__(256)
__attribute__((amdgpu_waves_per_eu(1, 1)))
void k_init(P29 a, float* __restrict__ ws)
{
    __shared__ __align__(16) float wl[PN];
    int tid = threadIdx.x;
#define STAGE(WS, BSi, h, K, padK, wdst, bdst) \
    { const float* Wp = a.p[WS]; const float* Bp = a.p[BSi]; \
      for (int i = tid; i < 3*(h)*(K); i += 256){ \
        int r = i/(K), k = i - r*(K); int g = r/(h), u0 = r - g*(h); \
        int sr = (g==0? u0 : (g==1? 2*(h)+u0 : 3*(h)+u0)); \
        wl[(wdst) + r*(padK) + k] = Wp[sr*(K) + k]; } \
      for (int i = tid; i < 3*(h); i += 256){ \
        int g = i/(h), u0 = i - g*(h); \
        int sr = (g==0? u0 : (g==1? 2*(h)+u0 : 3*(h)+u0)); \
        wl[(bdst) + i] = Bp[sr]; } }
    STAGE(19, 20, 32,  1,  1, PW0, PB0)
    STAGE(21, 22, 16, 32, 36, PW1, PB1)
    STAGE(23, 24,  8, 16, 20, PW2, PB2)
    STAGE(25, 26, 16,  8, 12, PW3, PB3)
    STAGE(27, 28, 32, 16, 20, PW4, PB4)
#undef STAGE
    { const float* s = a.p[17]; for (int i = tid; i < 32; i += 256) wl[POW+i] = s[i]; }
    if (tid == 0) wl[POB] = a.p[18][0];
    __syncthreads();

    int u = tid & 15;
    int gbase = (tid & 63) & 48;
    int gid = blockIdx.x * 16 + (tid >> 4);
    const float4* w4 = (const float4*)wl;
    {
        float xin = -8.f + (float)gid * (1.f/128.f);
        float lo = dunit(xin*wl[PW0+u]    + wl[PB0+u],
                         xin*wl[PW0+32+u] + wl[PB0+32+u],
                         xin*wl[PW0+64+u] + wl[PB0+64+u]);
        float hi = dunit(xin*wl[PW0+16+u] + wl[PB0+16+u],
                         xin*wl[PW0+48+u] + wl[PB0+48+u],
                         xin*wl[PW0+80+u] + wl[PB0+80+u]);
        float A0[32];
        #pragma unroll
        for (int k = 0; k < 16; k++) { A0[k] = __shfl(lo, gbase+k); A0[16+k] = __shfl(hi, gbase+k); }
        float gi = wl[PB1+u], gg = wl[PB1+16+u], go = wl[PB1+32+u];
        int bi_ = (PW1 + u*36)>>2, bg_ = (PW1 + (16+u)*36)>>2, bo_ = (PW1 + (32+u)*36)>>2;
        #pragma unroll
        for (int q = 0; q < 8; q++) {
            float4 wi = w4[bi_+q], wg = w4[bg_+q], wo = w4[bo_+q];
            float b0=A0[4*q], b1=A0[4*q+1], b2=A0[4*q+2], b3=A0[4*q+3];
            gi += b0*wi.x + b1*wi.y + b2*wi.z + b3*wi.w;
            gg += b0*wg.x + b1*wg.y + b2*wg.z + b3*wg.w;
            go += b0*wo.x + b1*wo.y + b2*wo.z + b3*wo.w;
        }
        float a1 = dunit(gi, gg, go);
        float A1[16];
        #pragma unroll
        for (int k = 0; k < 16; k++) A1[k] = __shfl(a1, gbase+k);
        int v = u & 7;
        gi = wl[PB2+v]; gg = wl[PB2+8+v]; go = wl[PB2+16+v];
        bi_ = (PW2 + v*20)>>2; bg_ = (PW2 + (8+v)*20)>>2; bo_ = (PW2 + (16+v)*20)>>2;
        #pragma unroll
        for (int q = 0; q < 4; q++) {
            float4 wi = w4[bi_+q], wg = w4[bg_+q], wo = w4[bo_+q];
            float b0=A1[4*q], b1=A1[4*q+1], b2=A1[4*q+2], b3=A1[4*q+3];
            gi += b0*wi.x + b1*wi.y + b2*wi.z + b3*wi.w;
            gg += b0*wg.x + b1*wg.y + b2*wg.z + b3*wg.w;
            go += b0*wo.x + b1*wo.y + b2*wo.z + b3*wo.w;
        }
        float a2 = dunit(gi, gg, go);
        float A2[8];
        #pragma unroll
        for (int k = 0; k < 8; k++) A2[k] = __shfl(a2, gbase+k);
        gi = wl[PB3+u]; gg = wl[PB3+16+u]; go = wl[PB3+32+u];
        bi_ = (PW3 + u*12)>>2; bg_ = (PW3 + (16+u)*12)>>2; bo_ = (PW3 + (32+u)*12)>>2;
        #pragma unroll
        for (int q = 0; q < 2; q++) {
            float4 wi = w4[bi_+q], wg = w4[bg_+q], wo = w4[bo_+q];
            float b0=A2[4*q], b1=A2[4*q+1], b2=A2[4*q+2], b3=A2[4*q+3];
            gi += b0*wi.x + b1*wi.y + b2*wi.z + b3*wi.w;
            gg += b0*wg.x + b1*wg.y + b2*wg.z + b3*wg.w;
            go += b0*wo.x + b1*wo.y + b2*wo.z + b3*wo.w;
        }
        float a3 = dunit(gi, gg, go);
        float A3[16];
        #pragma unroll
        for (int k = 0; k < 16; k++) A3[k] = __shfl(a3, gbase+k);
        float part;
        {
            float g0i = wl[PB4+u], g0g = wl[PB4+32+u], g0o = wl[PB4+64+u];
            float g1i = wl[PB4+16+u], g1g = wl[PB4+48+u], g1o = wl[PB4+80+u];
            int c0i = (PW4 + u*20)>>2,      c0g = (PW4 + (32+u)*20)>>2, c0o = (PW4 + (64+u)*20)>>2;
            int c1i = (PW4 + (16+u)*20)>>2, c1g = (PW4 + (48+u)*20)>>2, c1o = (PW4 + (80+u)*20)>>2;
            #pragma unroll
            for (int q = 0; q < 4; q++) {
                float b0=A3[4*q], b1=A3[4*q+1], b2=A3[4*q+2], b3=A3[4*q+3];
                float4 wi = w4[c0i+q], wg = w4[c0g+q], wo = w4[c0o+q];
                g0i += b0*wi.x + b1*wi.y + b2*wi.z + b3*wi.w;
                g0g += b0*wg.x + b1*wg.y + b2*wg.z + b3*wg.w;
                g0o += b0*wo.x + b1*wo.y + b2*wo.z + b3*wo.w;
                wi = w4[c1i+q]; wg = w4[c1g+q]; wo = w4[c1o+q];
                g1i += b0*wi.x + b1*wi.y + b2*wi.z + b3*wi.w;
                g1g += b0*wg.x + b1*wg.y + b2*wg.z + b3*wg.w;
                g1o += b0*wo.x + b1*wo.y + b2*wo.z + b3*wo.w;
            }
            part = dunit(g0i, g0g, g0o)*wl[POW+u] + dunit(g1i, g1g, g1o)*wl[POW+16+u];
        }
        part += __shfl_xor(part, 1);
        part += __shfl_xor(part, 2);
        part += __shfl_xor(part, 4);
        part += __shfl_xor(part, 8);
        if (u == 0 && gid < NTAB) ws[TAB + gid] = part + wl[POB];
    }
    if (blockIdx.x != 128) return;
    // ---- block 128: init states + batch-invariant decoder ----
    if (tid < 32) {
        int dir = tid >> 4, uu = tid & 15;
        const float* Wih = a.p[2 + 3*dir];
        const float* bia = a.p[4 + 3*dir];
        float s = dir ? -128.f : 128.f;
        float gi = s * Wih[uu]      + bia[uu];
        float gg = s * Wih[32 + uu] + bia[32 + uu];
        float go = s * Wih[48 + uu] + bia[48 + uu];
        float c0 = sigm(gi) * tanh_f(gg);
        ws[H0 + dir*32 + uu]      = sigm(go) * tanh_f(c0);
        ws[H0 + dir*32 + 16 + uu] = c0;
    }
    __shared__ float dh[16], dc[16];
    const float* Wih = a.p[12];
    const float* Whh = a.p[13];
    const float* bb  = a.p[14];
    const float* oW  = a.p[15];
    const float* ob  = a.p[16];
    float wii[16], wff[16], wgg[16], woo[16];
    float vii[16], vff[16], vgg[16], voo[16];
    float bi_r=0, bf_r=0, bg_r=0, bo_r=0;
    if (tid < 16) {
        int uu = tid;
        #pragma unroll
        for (int k = 0; k < 16; k++) {
            wii[k]=Wih[uu*16+k];      vii[k]=Whh[uu*16+k];
            wff[k]=Wih[(16+uu)*16+k]; vff[k]=Whh[(16+uu)*16+k];
            wgg[k]=Wih[(32+uu)*16+k]; vgg[k]=Whh[(32+uu)*16+k];
            woo[k]=Wih[(48+uu)*16+k]; voo[k]=Whh[(48+uu)*16+k];
        }
        bi_r=bb[uu]; bf_r=bb[16+uu]; bg_r=bb[32+uu]; bo_r=bb[48+uu];
        float gi = bi_r, gg = bg_r, go = bo_r;
        #pragma unroll
        for (int k = 0; k < 16; k++) {
            gi += 128.f * wii[k];
            gg += 128.f * wgg[k];
            go += 128.f * woo[k];
        }
        float c0 = sigm(gi) * tanh_f(gg);
        dc[tid] = c0; dh[tid] = sigm(go) * tanh_f(c0);
    }
    __syncthreads();
    for (int t = 0; t < 16; t++) {
        float rx[16], rh[16], cold = 0.f;
        if (tid < 16) {
            #pragma unroll
            for (int k = 0; k < 16; k++) { rx[k] = dc[k]; rh[k] = dh[k]; }
            cold = dc[tid];
        }
        __syncthreads();
        if (tid < 16) {
            float gi = bi_r, gf = bf_r, gg = bg_r, go = bo_r;
            #pragma unroll
            for (int k = 0; k < 16; k++) {
                gi += rx[k]*wii[k] + rh[k]*vii[k];
                gf += rx[k]*wff[k] + rh[k]*vff[k];
                gg += rx[k]*wgg[k] + rh[k]*vgg[k];
                go += rx[k]*woo[k] + rh[k]*voo[k];
            }
            float cn = sigm(gf)*cold + sigm(gi)*tanh_f(gg);
            dc[tid] = cn; dh[tid] = sigm(go)*tanh_f(cn);
        }
        __syncthreads();
        if (tid == 0) {
            float o = ob[0];
            #pragma unroll
            for (int k = 0; k < 16; k++) o += dh[k] * oW[k];
            ws[RECO + t] = o;
        }
        __syncthreads();
    }
}

// ---- generator LSTM: 16 lanes per (b,dir); packed v2f gates, LDS h-exchange.
//      waves_per_eu(2,2): pin occupancy goal so the allocator keeps the 64
//      weight VGPRs resident (r7: min-only bound -> 52 VGPR, reload/step). ----
__global__ __launch_bounds__(256)
__attribute__((amdgpu_waves_per_eu(2, 2)))
void k_lstm(P29 a, const int* __restrict__ masks, float* __restrict__ ws)
{
    __shared__ __align__(16) float lh[256];
    int tid = threadIdx.x;
    int T = blockIdx.x * 256 + tid;              // 0 .. 2^20-1
    int dir = T >> 19;
    int idx = T & 0x7FFFF;
    int u = idx & 15;
    int b = idx >> 4;
    int lane = tid & 63;
    int gbase = lane & 48;
    int gb = tid >> 4;
    const float* __restrict__ Whh = a.p[3 + 3*dir];
    v2f wif[16], wgo[16];
    #pragma unroll
    for (int q = 0; q < 4; q++) {
        float4 vi = ((const float4*)(Whh + (u)*16))[q];
        float4 vf = ((const float4*)(Whh + (16+u)*16))[q];
        float4 vg = ((const float4*)(Whh + (32+u)*16))[q];
        float4 vo = ((const float4*)(Whh + (48+u)*16))[q];
        wif[4*q+0] = (v2f){vi.x, vf.x}; wgo[4*q+0] = (v2f){vg.x, vo.x};
        wif[4*q+1] = (v2f){vi.y, vf.y}; wgo[4*q+1] = (v2f){vg.y, vo.y};
        wif[4*q+2] = (v2f){vi.z, vf.z}; wgo[4*q+2] = (v2f){vg.z, vo.z};
        wif[4*q+3] = (v2f){vi.w, vf.w}; wgo[4*q+3] = (v2f){vg.w, vo.w};
    }
    const float* __restrict__ Wih = a.p[2 + 3*dir];
    const float* __restrict__ bia = a.p[4 + 3*dir];
    v2f xif = (v2f){Wih[u], Wih[16+u]}, xgo = (v2f){Wih[32+u], Wih[48+u]};
    v2f bif = (v2f){bia[u], bia[16+u]}, bgo = (v2f){bia[32+u], bia[48+u]};
    v2f impw2[8];
    #pragma unroll
    for (int q = 0; q < 4; q++) {
        float4 v = ((const float4*)a.p[8])[q];
        impw2[2*q+0] = (v2f){v.x, v.y};
        impw2[2*q+1] = (v2f){v.z, v.w};
    }
    float impb = a.p[9][0];
    float x_own = a.p[0][(size_t)b*16 + u];
    int   m_own = masks[(size_t)b*16 + u];
    float h = ws[H0 + dir*32 + u];
    float c = ws[H0 + dir*32 + 16 + u];
    const float4* lhv = (const float4*)lh;
    for (int t = 0; t < 16; t++) {
        lh[tid] = h;                 // DS in-order per wave; own-wave slots only
        float4 h0 = lhv[gb*4+0], h1 = lhv[gb*4+1], h2 = lhv[gb*4+2], h3 = lhv[gb*4+3];
        v2f p0 = (v2f){h0.x, h0.y}, p1 = (v2f){h0.z, h0.w};
        v2f p2 = (v2f){h1.x, h1.y}, p3 = (v2f){h1.z, h1.w};
        v2f p4 = (v2f){h2.x, h2.y}, p5 = (v2f){h2.z, h2.w};
        v2f p6 = (v2f){h3.x, h3.y}, p7 = (v2f){h3.z, h3.w};
        v2f ia = (v2f){impb, 0.f};
        ia += p0*impw2[0]; ia += p1*impw2[1]; ia += p2*impw2[2]; ia += p3*impw2[3];
        ia += p4*impw2[4]; ia += p5*impw2[5]; ia += p6*impw2[6]; ia += p7*impw2[7];
        float imp = ia.x + ia.y;
        float xt = __shfl(x_own, gbase + t);
        int   mt = __shfl(m_own, gbase + t);
        float cc = mt ? imp : xt;
        v2f ccv = spl(cc);
        v2f gif = bif + ccv*xif;
        v2f ggo = bgo + ccv*xgo;
        gif += spl(h0.x)*wif[0];  ggo += spl(h0.x)*wgo[0];
        gif += spl(h0.y)*wif[1];  ggo += spl(h0.y)*wgo[1];
        gif += spl(h0.z)*wif[2];  ggo += spl(h0.z)*wgo[2];
        gif += spl(h0.w)*wif[3];  ggo += spl(h0.w)*wgo[3];
        gif += spl(h1.x)*wif[4];  ggo += spl(h1.x)*wgo[4];
        gif += spl(h1.y)*wif[5];  ggo += spl(h1.y)*wgo[5];
        gif += spl(h1.z)*wif[6];  ggo += spl(h1.z)*wgo[6];
        gif += spl(h1.w)*wif[7];  ggo += spl(h1.w)*wgo[7];
        gif += spl(h2.x)*wif[8];  ggo += spl(h2.x)*wgo[8];
        gif += spl(h2.y)*wif[9];  ggo += spl(h2.y)*wgo[9];
        gif += spl(h2.z)*wif[10]; ggo += spl(h2.z)*wgo[10];
        gif += spl(h2.w)*wif[11]; ggo += spl(h2.w)*wgo[11];
        gif += spl(h3.x)*wif[12]; ggo += spl(h3.x)*wgo[12];
        gif += spl(h3.y)*wif[13]; ggo += spl(h3.y)*wgo[13];
        gif += spl(h3.z)*wif[14]; ggo += spl(h3.z)*wgo[14];
        gif += spl(h3.w)*wif[15]; ggo += spl(h3.w)*wgo[15];
        float cn = sigm(gif.y)*c + sigm(gif.x)*tanh_f(ggo.x);
        c = cn;
        h = sigm(ggo.y)*tanh_f(cn);
    }
    ws[HFO + (size_t)dir*BS + (size_t)b*16 + u] = h;
}

// ---- k_post: 4 elements per thread (thread = (b, quarter)); h-row loaded
//      once per 4 outputs; fcW/rec/table staged in LDS; all I/O float4. ----
__global__ __launch_bounds__(256) void k_post(P29 a, const int* __restrict__ masks,
                                              const float* __restrict__ ws,
                                              float* __restrict__ out)
{
    __shared__ float tab[NTAB];
    __shared__ __align__(16) float fw[256];
    __shared__ __align__(16) float rec[16];
    __shared__ float fb[16];
    int tid = threadIdx.x;
    for (int i = tid; i < NTAB; i += 256) tab[i] = ws[TAB + i];
    fw[tid] = a.p[10][tid];
    if (tid < 16) { fb[tid] = a.p[11][tid]; rec[tid] = ws[RECO + tid]; }
    __syncthreads();
    int T = blockIdx.x * 256 + tid;      // 0 .. BB*4-1
    int b = T >> 2;
    int q = T & 3;
    int tq = q * 4;
    const float4* hf4 = (const float4*)(ws + HFO + (size_t)b*16);
    const float4* hb4 = (const float4*)(ws + HBO + (size_t)b*16);
    float4 s0, s1, s2, s3;
    {
        float4 f0=hf4[0], f1=hf4[1], f2=hf4[2], f3=hf4[3];
        float4 g0=hb4[0], g1=hb4[1], g2=hb4[2], g3=hb4[3];
        s0 = make_float4(f0.x+g0.x, f0.y+g0.y, f0.z+g0.z, f0.w+g0.w);
        s1 = make_float4(f1.x+g1.x, f1.y+g1.y, f1.z+g1.z, f1.w+g1.w);
        s2 = make_float4(f2.x+g2.x, f2.y+g2.y, f2.z+g2.z, f2.w+g2.w);
        s3 = make_float4(f3.x+g3.x, f3.y+g3.y, f3.z+g3.z, f3.w+g3.w);
    }
    float4 hq = (q==0) ? s0 : (q==1) ? s1 : (q==2) ? s2 : s3;
    float4 xv = *(const float4*)(a.p[0] + (size_t)b*16 + tq);
    int4   mv = *(const int4*)(masks + (size_t)b*16 + tq);
    float impv[4];
    impv[0] = mv.x ? xv.x : hq.x;
    impv[1] = mv.y ? xv.y : hq.y;
    impv[2] = mv.z ? xv.z : hq.z;
    impv[3] = mv.w ? xv.w : hq.w;
    float latv[4];
    #pragma unroll
    for (int j = 0; j < 4; j++) {
        int t = tq + j;
        const float4* wr = (const float4*)(fw + t*16);
        float4 w0=wr[0], w1=wr[1], w2=wr[2], w3=wr[3];
        float l = fb[t];
        l += s0.x*w0.x + s0.y*w0.y + s0.z*w0.z + s0.w*w0.w;
        l += s1.x*w1.x + s1.y*w1.y + s1.z*w1.z + s1.w*w1.w;
        l += s2.x*w2.x + s2.y*w2.y + s2.z*w2.z + s2.w*w2.w;
        l += s3.x*w3.x + s3.y*w3.y + s3.z*w3.z + s3.w*w3.w;
        latv[j] = l;
    }
    float dv[4];
    #pragma unroll
    for (int j = 0; j < 4; j++) {
        float xx = fminf(fmaxf(impv[j], -8.f), 8.f);
        float f = (xx + 8.f) * 128.f;
        float fi = floorf(f);
        int i = (int)fi; i = i > NTAB-2 ? NTAB-2 : i;
        float w = f - fi;
        dv[j] = fmaf(w, tab[i+1] - tab[i], tab[i]);
    }
    float4 rv = ((const float4*)rec)[q];
    size_t eo = (size_t)b*16 + tq;
    *(float4*)(out + eo)        = make_float4(impv[0], impv[1], impv[2], impv[3]);
    *(float4*)(out + BS + eo)   = make_float4(dv[0], dv[1], dv[2], dv[3]);
    *(float4*)(out + 2*BS + eo) = make_float4(latv[0], latv[1], latv[2], latv[3]);
    *(float4*)(out + 3*BS + eo) = rv;
}

extern "C" void kernel_launch(void* const* d_in, const int* in_sizes, int n_in,
                              void* d_out, int out_size, void* d_ws, size_t ws_size,
                              hipStream_t stream)
{
    float* ws = (float*)d_ws;
    P29 a;
    for (int i = 0; i < 29; i++) a.p[i] = (const float*)d_in[i];
    const int* masks = (const int*)d_in[1];
    k_init<<<129, 256, 0, stream>>>(a, ws);                   // table + prep
    k_lstm<<<(2*BB*16)/256, 256, 0, stream>>>(a, masks, ws);  // 16 lanes per (b,dir)
    k_post<<<(BB*4)/256, 256, 0, stream>>>(a, masks, ws, (float*)d_out);
}

// Round 9
// 169.422 us; speedup vs baseline: 1.1555x; 1.1555x over previous
//
#include <hip/hip_runtime.h>

#define BB 32768
#define BS (BB*16)   // 524288

typedef float v2f __attribute__((ext_vector_type(2)));
__device__ __forceinline__ v2f spl(float s){ return (v2f){s, s}; }

// ---- ws float offsets ----
#define RECO 64              // rec[16]
#define TAB  128             // disc F table, 2049 floats over [-8,8], step 1/128
#define NTAB 2049
#define HFO  8448            // final h fwd, B*16 floats
#define HBO  (HFO+BS)        // final h bwd

// ---- table-block LDS layout: gate-major (i,g,o; f dropped), padded strides ----
#define PW0 0
#define PB0 96
#define PW1 192    // 48 rows x 36
#define PB1 1920
#define PW2 1968   // 24 rows x 20
#define PB2 2448
#define PW3 2472   // 48 rows x 12
#define PB3 3048
#define PW4 3096   // 96 rows x 20
#define PB4 5016
#define POW 5112
#define POB 5144
#define PN  5148

// ---- LSTM-block LDS layout (inside same smem) ----
#define XOFF 576             // h region: 16 sets x 36; x region: 32 groups x 17

#define NLSTM 2048
#define NTABB 129            // table blocks
#define DECB  (NLSTM + NTABB)

__device__ __forceinline__ float sigm(float x){
    return __builtin_amdgcn_rcpf(1.f + __expf(-x));
}
__device__ __forceinline__ float tanh_f(float x){
    return 1.f - 2.f * __builtin_amdgcn_rcpf(1.f + __expf(2.f * x));
}
__device__ __forceinline__ float dunit(float gi, float gg, float go){
    return sigm(go) * tanh_f(sigm(gi) * tanh_f(gg));
}

struct P29 { const float* p[29]; };
// 0 values 1 masks 2-4 g_fwd(Wih,Whh,b) 5-7 g_bwd 8 impW 9 impb
// 10 fcW 11 fcb 12-14 dec(Wih,Whh,b) 15 dec_out_W 16 dec_out_b 17 disc_out_W
// 18 disc_out_b 19/20 d_W_0/d_b_0 ... 27/28 d_W_4/d_b_4

// ==== fused kernel: blocks 0..2047 LSTM (2 groups/thread, full unroll),
//      2048..2176 disc F table, 2177 decoder scan. ====
__global__ __launch_bounds__(256)
__attribute__((amdgpu_waves_per_eu(3, 8)))
void k_main(P29 a, const int* __restrict__ masks, float* __restrict__ ws)
{
    __shared__ __align__(16) float smem[PN];
    int tid = threadIdx.x;

    if (blockIdx.x < NLSTM) {
        // ---------------- LSTM path ----------------
        int lane = tid & 63;
        int gbase = lane & 48;
        int u = tid & 15;
        int setw = tid >> 4;                        // 0..15
        int gid0 = blockIdx.x * 32 + setw * 2;      // even global group id
        int dir = gid0 >> 15;
        int b0 = gid0 & 32767;
        const float* __restrict__ Whh = a.p[3 + 3*dir];
        v2f wif[16], wgo[16];
        #pragma unroll
        for (int q = 0; q < 4; q++) {
            float4 vi = ((const float4*)(Whh + (u)*16))[q];
            float4 vf = ((const float4*)(Whh + (16+u)*16))[q];
            float4 vg = ((const float4*)(Whh + (32+u)*16))[q];
            float4 vo = ((const float4*)(Whh + (48+u)*16))[q];
            wif[4*q+0] = (v2f){vi.x, vf.x}; wgo[4*q+0] = (v2f){vg.x, vo.x};
            wif[4*q+1] = (v2f){vi.y, vf.y}; wgo[4*q+1] = (v2f){vg.y, vo.y};
            wif[4*q+2] = (v2f){vi.z, vf.z}; wgo[4*q+2] = (v2f){vg.z, vo.z};
            wif[4*q+3] = (v2f){vi.w, vf.w}; wgo[4*q+3] = (v2f){vg.w, vo.w};
        }
        const float* __restrict__ Wih = a.p[2 + 3*dir];
        const float* __restrict__ bia = a.p[4 + 3*dir];
        v2f xif = (v2f){Wih[u], Wih[16+u]}, xgo = (v2f){Wih[32+u], Wih[48+u]};
        v2f bif = (v2f){bia[u], bia[16+u]}, bgo = (v2f){bia[32+u], bia[48+u]};
        v2f impw2[8];
        #pragma unroll
        for (int q = 0; q < 4; q++) {
            float4 v = ((const float4*)a.p[8])[q];
            impw2[2*q+0] = (v2f){v.x, v.y};
            impw2[2*q+1] = (v2f){v.z, v.w};
        }
        float impb = a.p[9][0];
        // per-lane inputs for the 2 groups
        float x0 = a.p[0][(size_t)b0*16 + u];
        float x1 = a.p[0][(size_t)(b0+1)*16 + u];
        int   q0 = masks[(size_t)b0*16 + u];
        int   q1 = masks[(size_t)(b0+1)*16 + u];
        unsigned mm0 = (unsigned)(__ballot(q0 != 0) >> gbase) & 0xffffu;
        unsigned mm1 = (unsigned)(__ballot(q1 != 0) >> gbase) & 0xffffu;
        // stage x into LDS (read-broadcast per step; padded stride 17)
        smem[XOFF + (setw*2+0)*17 + u] = x0;
        smem[XOFF + (setw*2+1)*17 + u] = x1;
        // initial state: x=+/-128, h=c=0 (f-gate dead) — same for both groups
        float sgn = dir ? -128.f : 128.f;
        float giI = sgn*xif.x + bif.x, ggI = sgn*xgo.x + bgo.x, goI = sgn*xgo.y + bgo.y;
        float cI = sigm(giI) * tanh_f(ggI);
        float hI = sigm(goI) * tanh_f(cI);
        float h[2] = {hI, hI}, c[2] = {cI, cI};
        unsigned mm[2] = {mm0, mm1};
        int wa = setw*36 + u;                        // h write addr (g1: +16)
        int ra = setw*9;                             // float4 idx of set h base (g: +4g)
        const float4* lhv = (const float4*)smem;
        #pragma unroll
        for (int t = 0; t < 16; t++) {
            smem[wa]      = h[0];
            smem[wa + 16] = h[1];
            #pragma unroll
            for (int g = 0; g < 2; g++) {
                float4 ha = lhv[ra + 4*g + 0];
                float4 hb = lhv[ra + 4*g + 1];
                float4 hc = lhv[ra + 4*g + 2];
                float4 hd = lhv[ra + 4*g + 3];
                v2f ia = (v2f){impb, 0.f};
                ia += (v2f){ha.x, ha.y} * impw2[0];
                ia += (v2f){ha.z, ha.w} * impw2[1];
                ia += (v2f){hb.x, hb.y} * impw2[2];
                ia += (v2f){hb.z, hb.w} * impw2[3];
                ia += (v2f){hc.x, hc.y} * impw2[4];
                ia += (v2f){hc.z, hc.w} * impw2[5];
                ia += (v2f){hd.x, hd.y} * impw2[6];
                ia += (v2f){hd.z, hd.w} * impw2[7];
                float imp = ia.x + ia.y;
                float xt = smem[XOFF + (setw*2+g)*17 + t];
                float cc = ((mm[g] >> t) & 1u) ? imp : xt;
                v2f ccv = spl(cc);
                v2f gif = bif + ccv*xif;
                v2f ggo = bgo + ccv*xgo;
                gif += spl(ha.x)*wif[0];  ggo += spl(ha.x)*wgo[0];
                gif += spl(ha.y)*wif[1];  ggo += spl(ha.y)*wgo[1];
                gif += spl(ha.z)*wif[2];  ggo += spl(ha.z)*wgo[2];
                gif += spl(ha.w)*wif[3];  ggo += spl(ha.w)*wgo[3];
                gif += spl(hb.x)*wif[4];  ggo += spl(hb.x)*wgo[4];
                gif += spl(hb.y)*wif[5];  ggo += spl(hb.y)*wgo[5];
                gif += spl(hb.z)*wif[6];  ggo += spl(hb.z)*wgo[6];
                gif += spl(hb.w)*wif[7];  ggo += spl(hb.w)*wgo[7];
                gif += spl(hc.x)*wif[8];  ggo += spl(hc.x)*wgo[8];
                gif += spl(hc.y)*wif[9];  ggo += spl(hc.y)*wgo[9];
                gif += spl(hc.z)*wif[10]; ggo += spl(hc.z)*wgo[10];
                gif += spl(hc.w)*wif[11]; ggo += spl(hc.w)*wgo[11];
                gif += spl(hd.x)*wif[12]; ggo += spl(hd.x)*wgo[12];
                gif += spl(hd.y)*wif[13]; ggo += spl(hd.y)*wgo[13];
                gif += spl(hd.z)*wif[14]; ggo += spl(hd.z)*wgo[14];
                gif += spl(hd.w)*wif[15]; ggo += spl(hd.w)*wgo[15];
                float cn = sigm(gif.y)*c[g] + sigm(gif.x)*tanh_f(ggo.x);
                c[g] = cn;
                h[g] = sigm(ggo.y)*tanh_f(cn);
            }
        }
        ws[HFO + (size_t)dir*BS + (size_t)b0*16 + u]     = h[0];
        ws[HFO + (size_t)dir*BS + (size_t)(b0+1)*16 + u] = h[1];
        return;
    }

    if (blockIdx.x < DECB) {
        // ---------------- F-table path: 16 lanes per entry ----------------
        float* wl = smem;
#define STAGE(WS, BSi, h, K, padK, wdst, bdst) \
    { const float* Wp = a.p[WS]; const float* Bp = a.p[BSi]; \
      for (int i = tid; i < 3*(h)*(K); i += 256){ \
        int r = i/(K), k = i - r*(K); int g = r/(h), u0 = r - g*(h); \
        int sr = (g==0? u0 : (g==1? 2*(h)+u0 : 3*(h)+u0)); \
        wl[(wdst) + r*(padK) + k] = Wp[sr*(K) + k]; } \
      for (int i = tid; i < 3*(h); i += 256){ \
        int g = i/(h), u0 = i - g*(h); \
        int sr = (g==0? u0 : (g==1? 2*(h)+u0 : 3*(h)+u0)); \
        wl[(bdst) + i] = Bp[sr]; } }
        STAGE(19, 20, 32,  1,  1, PW0, PB0)
        STAGE(21, 22, 16, 32, 36, PW1, PB1)
        STAGE(23, 24,  8, 16, 20, PW2, PB2)
        STAGE(25, 26, 16,  8, 12, PW3, PB3)
        STAGE(27, 28, 32, 16, 20, PW4, PB4)
#undef STAGE
        { const float* s = a.p[17]; for (int i = tid; i < 32; i += 256) wl[POW+i] = s[i]; }
        if (tid == 0) wl[POB] = a.p[18][0];
        __syncthreads();
        int u = tid & 15;
        int gbase = (tid & 63) & 48;
        int gid = (blockIdx.x - NLSTM) * 16 + (tid >> 4);
        const float4* w4 = (const float4*)wl;
        float xin = -8.f + (float)gid * (1.f/128.f);
        float lo = dunit(xin*wl[PW0+u]    + wl[PB0+u],
                         xin*wl[PW0+32+u] + wl[PB0+32+u],
                         xin*wl[PW0+64+u] + wl[PB0+64+u]);
        float hi = dunit(xin*wl[PW0+16+u] + wl[PB0+16+u],
                         xin*wl[PW0+48+u] + wl[PB0+48+u],
                         xin*wl[PW0+80+u] + wl[PB0+80+u]);
        float A0[32];
        #pragma unroll
        for (int k = 0; k < 16; k++) { A0[k] = __shfl(lo, gbase+k); A0[16+k] = __shfl(hi, gbase+k); }
        float gi = wl[PB1+u], gg = wl[PB1+16+u], go = wl[PB1+32+u];
        int bi_ = (PW1 + u*36)>>2, bg_ = (PW1 + (16+u)*36)>>2, bo_ = (PW1 + (32+u)*36)>>2;
        #pragma unroll
        for (int q = 0; q < 8; q++) {
            float4 wi = w4[bi_+q], wg = w4[bg_+q], wo = w4[bo_+q];
            float b0=A0[4*q], b1=A0[4*q+1], b2=A0[4*q+2], b3=A0[4*q+3];
            gi += b0*wi.x + b1*wi.y + b2*wi.z + b3*wi.w;
            gg += b0*wg.x + b1*wg.y + b2*wg.z + b3*wg.w;
            go += b0*wo.x + b1*wo.y + b2*wo.z + b3*wo.w;
        }
        float a1 = dunit(gi, gg, go);
        float A1[16];
        #pragma unroll
        for (int k = 0; k < 16; k++) A1[k] = __shfl(a1, gbase+k);
        int v = u & 7;
        gi = wl[PB2+v]; gg = wl[PB2+8+v]; go = wl[PB2+16+v];
        bi_ = (PW2 + v*20)>>2; bg_ = (PW2 + (8+v)*20)>>2; bo_ = (PW2 + (16+v)*20)>>2;
        #pragma unroll
        for (int q = 0; q < 4; q++) {
            float4 wi = w4[bi_+q], wg = w4[bg_+q], wo = w4[bo_+q];
            float b0=A1[4*q], b1=A1[4*q+1], b2=A1[4*q+2], b3=A1[4*q+3];
            gi += b0*wi.x + b1*wi.y + b2*wi.z + b3*wi.w;
            gg += b0*wg.x + b1*wg.y + b2*wg.z + b3*wg.w;
            go += b0*wo.x + b1*wo.y + b2*wo.z + b3*wo.w;
        }
        float a2 = dunit(gi, gg, go);
        float A2[8];
        #pragma unroll
        for (int k = 0; k < 8; k++) A2[k] = __shfl(a2, gbase+k);
        gi = wl[PB3+u]; gg = wl[PB3+16+u]; go = wl[PB3+32+u];
        bi_ = (PW3 + u*12)>>2; bg_ = (PW3 + (16+u)*12)>>2; bo_ = (PW3 + (32+u)*12)>>2;
        #pragma unroll
        for (int q = 0; q < 2; q++) {
            float4 wi = w4[bi_+q], wg = w4[bg_+q], wo = w4[bo_+q];
            float b0=A2[4*q], b1=A2[4*q+1], b2=A2[4*q+2], b3=A2[4*q+3];
            gi += b0*wi.x + b1*wi.y + b2*wi.z + b3*wi.w;
            gg += b0*wg.x + b1*wg.y + b2*wg.z + b3*wg.w;
            go += b0*wo.x + b1*wo.y + b2*wo.z + b3*wo.w;
        }
        float a3 = dunit(gi, gg, go);
        float A3[16];
        #pragma unroll
        for (int k = 0; k < 16; k++) A3[k] = __shfl(a3, gbase+k);
        float part;
        {
            float g0i = wl[PB4+u], g0g = wl[PB4+32+u], g0o = wl[PB4+64+u];
            float g1i = wl[PB4+16+u], g1g = wl[PB4+48+u], g1o = wl[PB4+80+u];
            int c0i = (PW4 + u*20)>>2,      c0g = (PW4 + (32+u)*20)>>2, c0o = (PW4 + (64+u)*20)>>2;
            int c1i = (PW4 + (16+u)*20)>>2, c1g = (PW4 + (48+u)*20)>>2, c1o = (PW4 + (80+u)*20)>>2;
            #pragma unroll
            for (int q = 0; q < 4; q++) {
                float b0=A3[4*q], b1=A3[4*q+1], b2=A3[4*q+2], b3=A3[4*q+3];
                float4 wi = w4[c0i+q], wg = w4[c0g+q], wo = w4[c0o+q];
                g0i += b0*wi.x + b1*wi.y + b2*wi.z + b3*wi.w;
                g0g += b0*wg.x + b1*wg.y + b2*wg.z + b3*wg.w;
                g0o += b0*wo.x + b1*wo.y + b2*wo.z + b3*wo.w;
                wi = w4[c1i+q]; wg = w4[c1g+q]; wo = w4[c1o+q];
                g1i += b0*wi.x + b1*wi.y + b2*wi.z + b3*wi.w;
                g1g += b0*wg.x + b1*wg.y + b2*wg.z + b3*wg.w;
                g1o += b0*wo.x + b1*wo.y + b2*wo.z + b3*wo.w;
            }
            part = dunit(g0i, g0g, g0o)*wl[POW+u] + dunit(g1i, g1g, g1o)*wl[POW+16+u];
        }
        part += __shfl_xor(part, 1);
        part += __shfl_xor(part, 2);
        part += __shfl_xor(part, 4);
        part += __shfl_xor(part, 8);
        if (u == 0 && gid < NTAB) ws[TAB + gid] = part + wl[POB];
        return;
    }

    // ---------------- decoder block (batch-invariant scan) ----------------
    {
        float* dh = smem;       // [16]
        float* dc = smem + 16;  // [16]
        const float* Wih = a.p[12];
        const float* Whh = a.p[13];
        const float* bb  = a.p[14];
        const float* oW  = a.p[15];
        const float* ob  = a.p[16];
        float wii[16], wff[16], wgg[16], woo[16];
        float vii[16], vff[16], vgg[16], voo[16];
        float bi_r=0, bf_r=0, bg_r=0, bo_r=0;
        if (tid < 16) {
            int uu = tid;
            #pragma unroll
            for (int k = 0; k < 16; k++) {
                wii[k]=Wih[uu*16+k];      vii[k]=Whh[uu*16+k];
                wff[k]=Wih[(16+uu)*16+k]; vff[k]=Whh[(16+uu)*16+k];
                wgg[k]=Wih[(32+uu)*16+k]; vgg[k]=Whh[(32+uu)*16+k];
                woo[k]=Wih[(48+uu)*16+k]; voo[k]=Whh[(48+uu)*16+k];
            }
            bi_r=bb[uu]; bf_r=bb[16+uu]; bg_r=bb[32+uu]; bo_r=bb[48+uu];
            float gi = bi_r, gg = bg_r, go = bo_r;
            #pragma unroll
            for (int k = 0; k < 16; k++) {
                gi += 128.f * wii[k];
                gg += 128.f * wgg[k];
                go += 128.f * woo[k];
            }
            float c0 = sigm(gi) * tanh_f(gg);
            dc[tid] = c0; dh[tid] = sigm(go) * tanh_f(c0);
        }
        __syncthreads();
        for (int t = 0; t < 16; t++) {
            float rx[16], rh[16], cold = 0.f;
            if (tid < 16) {
                #pragma unroll
                for (int k = 0; k < 16; k++) { rx[k] = dc[k]; rh[k] = dh[k]; }
                cold = dc[tid];
            }
            __syncthreads();
            if (tid < 16) {
                float gi = bi_r, gf = bf_r, gg = bg_r, go = bo_r;
                #pragma unroll
                for (int k = 0; k < 16; k++) {
                    gi += rx[k]*wii[k] + rh[k]*vii[k];
                    gf += rx[k]*wff[k] + rh[k]*vff[k];
                    gg += rx[k]*wgg[k] + rh[k]*vgg[k];
                    go += rx[k]*woo[k] + rh[k]*voo[k];
                }
                float cn = sigm(gf)*cold + sigm(gi)*tanh_f(gg);
                dc[tid] = cn; dh[tid] = sigm(go)*tanh_f(cn);
            }
            __syncthreads();
            if (tid == 0) {
                float o = ob[0];
                #pragma unroll
                for (int k = 0; k < 16; k++) o += dh[k] * oW[k];
                ws[RECO + t] = o;
            }
            __syncthreads();
        }
    }
}

// ---- k_post: 4 elements per thread; fcW/rec/table staged in LDS ----
__global__ __launch_bounds__(256) void k_post(P29 a, const int* __restrict__ masks,
                                              const float* __restrict__ ws,
                                              float* __restrict__ out)
{
    __shared__ float tab[NTAB];
    __shared__ __align__(16) float fw[256];
    __shared__ __align__(16) float rec[16];
    __shared__ float fb[16];
    int tid = threadIdx.x;
    for (int i = tid; i < NTAB; i += 256) tab[i] = ws[TAB + i];
    fw[tid] = a.p[10][tid];
    if (tid < 16) { fb[tid] = a.p[11][tid]; rec[tid] = ws[RECO + tid]; }
    __syncthreads();
    int T = blockIdx.x * 256 + tid;      // 0 .. BB*4-1
    int b = T >> 2;
    int q = T & 3;
    int tq = q * 4;
    const float4* hf4 = (const float4*)(ws + HFO + (size_t)b*16);
    const float4* hb4 = (const float4*)(ws + HBO + (size_t)b*16);
    float4 s0, s1, s2, s3;
    {
        float4 f0=hf4[0], f1=hf4[1], f2=hf4[2], f3=hf4[3];
        float4 g0=hb4[0], g1=hb4[1], g2=hb4[2], g3=hb4[3];
        s0 = make_float4(f0.x+g0.x, f0.y+g0.y, f0.z+g0.z, f0.w+g0.w);
        s1 = make_float4(f1.x+g1.x, f1.y+g1.y, f1.z+g1.z, f1.w+g1.w);
        s2 = make_float4(f2.x+g2.x, f2.y+g2.y, f2.z+g2.z, f2.w+g2.w);
        s3 = make_float4(f3.x+g3.x, f3.y+g3.y, f3.z+g3.z, f3.w+g3.w);
    }
    float4 hq = (q==0) ? s0 : (q==1) ? s1 : (q==2) ? s2 : s3;
    float4 xv = *(const float4*)(a.p[0] + (size_t)b*16 + tq);
    int4   mv = *(const int4*)(masks + (size_t)b*16 + tq);
    float impv[4];
    impv[0] = mv.x ? xv.x : hq.x;
    impv[1] = mv.y ? xv.y : hq.y;
    impv[2] = mv.z ? xv.z : hq.z;
    impv[3] = mv.w ? xv.w : hq.w;
    float latv[4];
    #pragma unroll
    for (int j = 0; j < 4; j++) {
        int t = tq + j;
        const float4* wr = (const float4*)(fw + t*16);
        float4 w0=wr[0], w1=wr[1], w2=wr[2], w3=wr[3];
        float l = fb[t];
        l += s0.x*w0.x + s0.y*w0.y + s0.z*w0.z + s0.w*w0.w;
        l += s1.x*w1.x + s1.y*w1.y + s1.z*w1.z + s1.w*w1.w;
        l += s2.x*w2.x + s2.y*w2.y + s2.z*w2.z + s2.w*w2.w;
        l += s3.x*w3.x + s3.y*w3.y + s3.z*w3.z + s3.w*w3.w;
        latv[j] = l;
    }
    float dv[4];
    #pragma unroll
    for (int j = 0; j < 4; j++) {
        float xx = fminf(fmaxf(impv[j], -8.f), 8.f);
        float f = (xx + 8.f) * 128.f;
        float fi = floorf(f);
        int i = (int)fi; i = i > NTAB-2 ? NTAB-2 : i;
        float w = f - fi;
        dv[j] = fmaf(w, tab[i+1] - tab[i], tab[i]);
    }
    float4 rv = ((const float4*)rec)[q];
    size_t eo = (size_t)b*16 + tq;
    *(float4*)(out + eo)        = make_float4(impv[0], impv[1], impv[2], impv[3]);
    *(float4*)(out + BS + eo)   = make_float4(dv[0], dv[1], dv[2], dv[3]);
    *(float4*)(out + 2*BS + eo) = make_float4(latv[0], latv[1], latv[2], latv[3]);
    *(float4*)(out + 3*BS + eo) = rv;
}

extern "C" void kernel_launch(void* const* d_in, const int* in_sizes, int n_in,
                              void* d_out, int out_size, void* d_ws, size_t ws_size,
                              hipStream_t stream)
{
    float* ws = (float*)d_ws;
    P29 a;
    for (int i = 0; i < 29; i++) a.p[i] = (const float*)d_in[i];
    const int* masks = (const int*)d_in[1];
    k_main<<<NLSTM + NTABB + 1, 256, 0, stream>>>(a, masks, ws);
    k_post<<<(BB*4)/256, 256, 0, stream>>>(a, masks, ws, (float*)d_out);
}